// Round 9
// baseline (163.605 us; speedup 1.0000x reference)
//
#include <hip/hip_runtime.h>
#include <stdint.h>

// Problem constants
#define BB 16
#define CC 512
#define CQK 64
#define NN 1024   // H*W = 32*32

typedef __attribute__((ext_vector_type(8))) short bf16x8;
typedef __attribute__((ext_vector_type(4))) short short4v;
typedef __attribute__((ext_vector_type(4))) float f32x4;

static __device__ __forceinline__ unsigned short f2bf(float f) {
  uint32_t u = __float_as_uint(f);
  u += 0x7FFFu + ((u >> 16) & 1u);
  return (unsigned short)(u >> 16);
}

// Async global->LDS, 16B per lane. LDS dest = wave-uniform base + lane*16.
static __device__ __forceinline__ void gll16(const unsigned short* g, unsigned short* l) {
  const __attribute__((address_space(1))) unsigned int* gp =
      reinterpret_cast<const __attribute__((address_space(1))) unsigned int*>(
          reinterpret_cast<uintptr_t>(g));
  __attribute__((address_space(3))) unsigned int* lp =
      reinterpret_cast<__attribute__((address_space(3))) unsigned int*>(
          (unsigned int)reinterpret_cast<uintptr_t>(l));
  __builtin_amdgcn_global_load_lds(gp, lp, 16, 0, 0);
}

// ---------------------------------------------------------------------------
// Kernel 1: transpose x -> xT bf16 + weight pack (R8 body, unchanged).
// grid (N/64=16, C/64=8, B=16), block 256
// ---------------------------------------------------------------------------
__global__ __launch_bounds__(256) void k_prep(
    const float* __restrict__ x, unsigned short* __restrict__ xT,
    const float* __restrict__ Wq, const float* __restrict__ Wk,
    const float* __restrict__ Wv, unsigned short* __restrict__ Wall) {
  __shared__ float tile[64][65];  // 16.6 KB
  int b = blockIdx.z;
  int c0 = blockIdx.y * 64;
  int n0 = blockIdx.x * 64;
  int t = threadIdx.x;

  int flat = ((int)blockIdx.z * gridDim.y + blockIdx.y) * gridDim.x + blockIdx.x;
  if (flat < 320) {
    int e = (flat * 256 + t) * 4;
    int o = e >> 9;
    int c = e & 511;
    const float* src;
    if (o < 64)        src = Wq + (size_t)o * 512;
    else if (o < 128)  src = Wk + (size_t)(o - 64) * 512;
    else               src = Wv + (size_t)(o - 128) * 512;
    float4 v = *(const float4*)(src + c);
    short4v pk;
    pk[0] = (short)f2bf(v.x); pk[1] = (short)f2bf(v.y);
    pk[2] = (short)f2bf(v.z); pk[3] = (short)f2bf(v.w);
    *(short4v*)(Wall + e) = pk;
  }

  int r = t >> 2;        // 0..63 : c-row within tile
  int cg = t & 3;        // 0..3  : 16-float column group
  const float* xp = x + ((size_t)(b * CC + c0 + r)) * NN + n0;
#pragma unroll
  for (int k = 0; k < 4; k++) {
    float4 v = *(const float4*)(xp + k * 16 + cg * 4);
    int cb = k * 16 + cg * 4;
    tile[r][cb + 0] = v.x;
    tile[r][cb + 1] = v.y;
    tile[r][cb + 2] = v.z;
    tile[r][cb + 3] = v.w;
  }
  __syncthreads();

  int n = t >> 2;        // 0..63 : n-row of output
  unsigned short* xq = xT + ((size_t)(b * NN + n0 + n)) * CC + c0 + cg * 16;
  short4v p[4];
#pragma unroll
  for (int q = 0; q < 4; q++) {
#pragma unroll
    for (int j = 0; j < 4; j++) p[q][j] = (short)f2bf(tile[cg * 16 + q * 4 + j][n]);
  }
  *(short4v*)(xq + 0) = p[0];
  *(short4v*)(xq + 4) = p[1];
  *(short4v*)(xq + 8) = p[2];
  *(short4v*)(xq + 12) = p[3];
}

// ---------------------------------------------------------------------------
// Kernel 2: GEMM1 with COUNTED-vmcnt double buffer (T4 / m201 pattern).
//   Old: stage(k+1); ds_read(k); MFMA; __syncthreads()  <- drains vmcnt(0),
//   i.e. waits for the just-issued stage every step (structural stall).
//   New: stage(k+1); s_waitcnt vmcnt(4) (only tile k's 4 loads must land;
//   the new 4 stay in flight); raw s_barrier; ds_read+MFMA; raw s_barrier
//   (readers done -> next iter may overwrite). sched_barrier(0) fences
//   prevent hipcc from moving the stage or ds_reads across the asm.
// ---------------------------------------------------------------------------
__global__ __launch_bounds__(256) void k_gemm1(
    const unsigned short* __restrict__ Wall, const unsigned short* __restrict__ xT,
    const float* __restrict__ bq, const float* __restrict__ bk,
    const float* __restrict__ bv,
    unsigned short* __restrict__ qkT, unsigned short* __restrict__ vbuf) {
  __shared__ __align__(16) unsigned short ldsA[2][128 * 32];
  __shared__ __align__(16) unsigned short ldsB[2][128 * 32];
  int bid = blockIdx.x;
  int swz = (bid & 7) * 80 + (bid >> 3);
  int nx = swz & 7;
  int rest = swz >> 3;
  int oy = rest % 5;
  int b = rest / 5;
  int o0 = oy * 128;
  int n0 = nx * 128;
  int t = threadIdx.x;
  int w = t >> 6, l = t & 63;
  int wm = w & 1, wn = w >> 1;
  int lr = l & 15, lq = l >> 4;

  f32x4 acc[4][4];
#pragma unroll
  for (int i = 0; i < 4; i++)
#pragma unroll
    for (int j = 0; j < 4; j++) acc[i][j] = (f32x4){0.f, 0.f, 0.f, 0.f};

  const unsigned short* Ab = Wall + (size_t)o0 * CC;
  const unsigned short* Bb = xT + ((size_t)b * NN + n0) * CC;
  int srow = t >> 2;
  int skq = (t & 3) * 8;
  int ldsw = (t >> 6) * 512;

  // Stage k-tile 0 into buffer 0 (4 loads; drained by the s=0 vmcnt(4)).
#pragma unroll
  for (int p = 0; p < 2; p++) {
    int r = p * 64 + srow;
    gll16(&Ab[(size_t)r * CC + skq], &ldsA[0][p * 2048 + ldsw]);
    gll16(&Bb[(size_t)r * CC + skq], &ldsB[0][p * 2048 + ldsw]);
  }

  for (int s = 0; s < 16; ++s) {
    int cur = s & 1;
    if (s < 15) {
      int kt = (s + 1) * 32;
#pragma unroll
      for (int p = 0; p < 2; p++) {
        int r = p * 64 + srow;
        gll16(&Ab[(size_t)r * CC + kt + skq], &ldsA[cur ^ 1][p * 2048 + ldsw]);
        gll16(&Bb[(size_t)r * CC + kt + skq], &ldsB[cur ^ 1][p * 2048 + ldsw]);
      }
    }
    __builtin_amdgcn_sched_barrier(0);
    if (s < 15) {
      asm volatile("s_waitcnt vmcnt(4)" ::: "memory");  // tile s's loads done; next 4 in flight
    } else {
      asm volatile("s_waitcnt vmcnt(0)" ::: "memory");  // last tile: full drain
    }
    __builtin_amdgcn_sched_barrier(0);
    __builtin_amdgcn_s_barrier();  // all waves see buf[cur] complete

    bf16x8 af[4], bfr[4];
#pragma unroll
    for (int i = 0; i < 4; i++)
      af[i] = *(const bf16x8*)(&ldsA[cur][(wm * 64 + i * 16 + lr) * 32 + lq * 8]);
#pragma unroll
    for (int j = 0; j < 4; j++)
      bfr[j] = *(const bf16x8*)(&ldsB[cur][(wn * 64 + j * 16 + lr) * 32 + lq * 8]);
#pragma unroll
    for (int i = 0; i < 4; i++)
#pragma unroll
      for (int j = 0; j < 4; j++)
        acc[i][j] = __builtin_amdgcn_mfma_f32_16x16x32_bf16(af[i], bfr[j], acc[i][j], 0, 0, 0);

    __builtin_amdgcn_s_barrier();  // readers of buf[cur] done -> may overwrite next iter
  }

  if (o0 == 0) {
#pragma unroll
    for (int i = 0; i < 4; i++) {
      int ob = wm * 64 + i * 16 + lq * 4;
#pragma unroll
      for (int j = 0; j < 4; j++) {
        int n = n0 + wn * 64 + j * 16 + lr;
        short4v pk;
#pragma unroll
        for (int r = 0; r < 4; r++) {
          int o = ob + r;
          float bias = (o < 64) ? bq[o] : bk[o - 64];
          pk[r] = (short)f2bf(acc[i][j][r] + bias);
        }
        *(short4v*)(&qkT[((size_t)b * NN + n) * 128 + ob]) = pk;
      }
    }
  } else {
#pragma unroll
    for (int i = 0; i < 4; i++) {
#pragma unroll
      for (int r = 0; r < 4; r++) {
        int o = o0 + wm * 64 + i * 16 + lq * 4 + r;
        int c = o - 128;
        float bias = bv[c];
#pragma unroll
        for (int j = 0; j < 4; j++) {
          int n = n0 + wn * 64 + j * 16 + lr;
          vbuf[((size_t)b * CC + c) * NN + n] = f2bf(acc[i][j][r] + bias);
        }
      }
    }
  }
}

// ---------------------------------------------------------------------------
// Kernel 3: one-pass flash, MC 64->128 (16 chunks -> 8). R7 showed wall is
//   dominated by a fixed per-chunk cost (~6600cy/chunk vs ~1200cy of issue
//   work); halving chunk count amortizes barriers + P round-trip + refill
//   over 2x work. Structure per chunk: {V ks0 + next-K loads | barrier |
//   P-write(32) + next-S(2 hg groups) | barrier | PV ks0..3 with V ks1..3
//   loads interleaved between MFMA groups}. P = 64 x 136 (17.4 KB).
//   512 blocks / 2-way c-split / acc[4][4] retained (R1-proven).
// ---------------------------------------------------------------------------
#define QT 64
#define MC 128
#define PSTR 136  // ushort units; 272B row stride (16B-aligned; bank step 4)

__global__ __launch_bounds__(256, 2) void k_flash(
    const unsigned short* __restrict__ qkT, const unsigned short* __restrict__ vbuf,
    const float* __restrict__ x, const float* __restrict__ gamma,
    float* __restrict__ out) {
  __shared__ __align__(16) unsigned short P[QT * PSTR];  // 17408 B
  __shared__ float red[4 * QT];                          // 1024 B
  __shared__ float fin[QT];                              // 256 B

  // XCD-aware swizzle: hw block h -> logical id (h%8)*64 + h/8 (512 = 8*64).
  int bid = blockIdx.x;
  int swz = (bid & 7) * 64 + (bid >> 3);
  int ntile = swz & 15;
  int chalf = (swz >> 4) & 1;
  int b = swz >> 5;
  int n0 = ntile * QT;
  int t = threadIdx.x;
  int w = t >> 6, l = t & 63;
  int lr = l & 15, lq = l >> 4;
  int lq8 = lq * 8;
  const unsigned short* qk = qkT + (size_t)b * NN * 128;
  const unsigned short* Vb = vbuf + ((size_t)b * CC + chalf * 256 + w * 64) * NN;

  // Q fragments (constant over all chunks)
  bf16x8 aq[4][2];
#pragma unroll
  for (int nj = 0; nj < 4; nj++)
#pragma unroll
    for (int ks = 0; ks < 2; ks++)
      aq[nj][ks] = *(const bf16x8*)(&qk[(size_t)(n0 + nj * 16 + lr) * 128 + ks * 32 + lq8]);

  f32x4 acc[4][4];  // [ci][nj]
#pragma unroll
  for (int ci = 0; ci < 4; ci++)
#pragma unroll
    for (int nj = 0; nj < 4; nj++) acc[ci][nj] = (f32x4){0.f, 0.f, 0.f, 0.f};
  float sreg[4][4];
#pragma unroll
  for (int nj = 0; nj < 4; nj++)
#pragma unroll
    for (int r = 0; r < 4; r++) sreg[nj][r] = 0.f;

  // Prologue: scores+exp for chunk 0 (both 64-key half-groups hg)
  float ev[4][2][4];
#pragma unroll
  for (int hg = 0; hg < 2; hg++) {
    int mrow = hg * 64 + w * 16 + lr;
    bf16x8 kf0 = *(const bf16x8*)(&qk[(size_t)mrow * 128 + 64 + lq8]);
    bf16x8 kf1 = *(const bf16x8*)(&qk[(size_t)mrow * 128 + 96 + lq8]);
#pragma unroll
    for (int nj = 0; nj < 4; nj++) {
      f32x4 s = (f32x4){0.f, 0.f, 0.f, 0.f};
      s = __builtin_amdgcn_mfma_f32_16x16x32_bf16(aq[nj][0], kf0, s, 0, 0, 0);
      s = __builtin_amdgcn_mfma_f32_16x16x32_bf16(aq[nj][1], kf1, s, 0, 0, 0);
#pragma unroll
      for (int r = 0; r < 4; r++) {
        float e = __expf(s[r]);
        ev[nj][hg][r] = e;
        sreg[nj][r] += e;
      }
    }
  }

  for (int m0 = 0; m0 < NN; m0 += MC) {
    bool hn = (m0 + MC < NN);
    // V ks=0 for this chunk (latency covered by barrier region below).
    bf16x8 vf[4];
#pragma unroll
    for (int ci = 0; ci < 4; ci++)
      vf[ci] = *(const bf16x8*)(&Vb[(size_t)(ci * 16 + lr) * NN + m0 + lq8]);

    // Next-chunk K fragments (consumed after barrier 1).
    bf16x8 kfn[2][2];
    if (hn) {
#pragma unroll
      for (int hg = 0; hg < 2; hg++) {
        int mrow = m0 + MC + hg * 64 + w * 16 + lr;
        kfn[hg][0] = *(const bf16x8*)(&qk[(size_t)mrow * 128 + 64 + lq8]);
        kfn[hg][1] = *(const bf16x8*)(&qk[(size_t)mrow * 128 + 96 + lq8]);
      }
    }

    __syncthreads();  // all PV reads of previous chunk's P complete
#pragma unroll
    for (int nj = 0; nj < 4; nj++)
#pragma unroll
      for (int hg = 0; hg < 2; hg++)
#pragma unroll
        for (int r = 0; r < 4; r++)
          P[(nj * 16 + lq * 4 + r) * PSTR + hg * 64 + w * 16 + lr] = f2bf(ev[nj][hg][r]);

    // Compute scores+exp for NEXT chunk while P settles.
    if (hn) {
#pragma unroll
      for (int hg = 0; hg < 2; hg++)
#pragma unroll
        for (int nj = 0; nj < 4; nj++) {
          f32x4 s = (f32x4){0.f, 0.f, 0.f, 0.f};
          s = __builtin_amdgcn_mfma_f32_16x16x32_bf16(aq[nj][0], kfn[hg][0], s, 0, 0, 0);
          s = __builtin_amdgcn_mfma_f32_16x16x32_bf16(aq[nj][1], kfn[hg][1], s, 0, 0, 0);
#pragma unroll
          for (int r = 0; r < 4; r++) {
            float e = __expf(s[r]);
            ev[nj][hg][r] = e;
            sreg[nj][r] += e;
          }
        }
    }
    __syncthreads();  // P ready

    // PV over 4 key-slices; V for slice ks+1 loaded under slice ks's MFMAs.
#pragma unroll
    for (int ks = 0; ks < 4; ks++) {
      bf16x8 vn[4];
      if (ks < 3) {
#pragma unroll
        for (int ci = 0; ci < 4; ci++)
          vn[ci] = *(const bf16x8*)(&Vb[(size_t)(ci * 16 + lr) * NN + m0 + (ks + 1) * 32 + lq8]);
      }
#pragma unroll
      for (int nj = 0; nj < 4; nj++) {
        bf16x8 pf = *(const bf16x8*)(&P[(nj * 16 + lr) * PSTR + ks * 32 + lq8]);
#pragma unroll
        for (int ci = 0; ci < 4; ci++)
          acc[ci][nj] = __builtin_amdgcn_mfma_f32_16x16x32_bf16(vf[ci], pf, acc[ci][nj], 0, 0, 0);
      }
      if (ks < 3) {
#pragma unroll
        for (int ci = 0; ci < 4; ci++) vf[ci] = vn[ci];
      }
    }
  }

  // ---- final row sums (across 16 lr lanes, then 4 waves) ----
#pragma unroll
  for (int nj = 0; nj < 4; nj++)
#pragma unroll
    for (int r = 0; r < 4; r++) {
#pragma unroll
      for (int d = 1; d < 16; d <<= 1) sreg[nj][r] += __shfl_xor(sreg[nj][r], d, 64);
    }
  __syncthreads();
  if (lr == 0) {
#pragma unroll
    for (int nj = 0; nj < 4; nj++)
#pragma unroll
      for (int r = 0; r < 4; r++) red[w * QT + nj * 16 + lq * 4 + r] = sreg[nj][r];
  }
  __syncthreads();
  if (t < QT) {
    float ssum = red[t] + red[QT + t] + red[2 * QT + t] + red[3 * QT + t];
    fin[t] = ssum;
  }
  __syncthreads();

  float invL[4];
#pragma unroll
  for (int nj = 0; nj < 4; nj++) invL[nj] = 1.0f / fin[nj * 16 + lr];
  float g = gamma[0];
#pragma unroll
  for (int ci = 0; ci < 4; ci++) {
#pragma unroll
    for (int r = 0; r < 4; r++) {
      int c = chalf * 256 + w * 64 + ci * 16 + lq * 4 + r;
#pragma unroll
      for (int nj = 0; nj < 4; nj++) {
        size_t idx = ((size_t)b * CC + c) * NN + n0 + nj * 16 + lr;
        out[idx] = g * acc[ci][nj][r] * invL[nj] + x[idx];
      }
    }
  }
}

// ---------------------------------------------------------------------------
extern "C" void kernel_launch(void* const* d_in, const int* in_sizes, int n_in,
                              void* d_out, int out_size, void* d_ws, size_t ws_size,
                              hipStream_t stream) {
  (void)in_sizes; (void)n_in; (void)out_size; (void)ws_size;
  const float* x     = (const float*)d_in[0];
  const float* Wq    = (const float*)d_in[1];
  const float* bq    = (const float*)d_in[2];
  const float* Wk    = (const float*)d_in[3];
  const float* bk    = (const float*)d_in[4];
  const float* Wv    = (const float*)d_in[5];
  const float* bv    = (const float*)d_in[6];
  const float* gamma = (const float*)d_in[7];
  float* out = (float*)d_out;

  char* ws = (char*)d_ws;
  unsigned short* Wall = (unsigned short*)(ws);                       // 655,360 B
  unsigned short* xT   = (unsigned short*)(ws + 655360);              // 16,777,216 B
  unsigned short* qkT  = (unsigned short*)(ws + 655360 + 16777216);   // 4,194,304 B
  unsigned short* vbuf = (unsigned short*)(ws + 655360 + 16777216 + 4194304);  // 16,777,216 B
  // total ~38.4 MB

  k_prep<<<dim3(NN / 64, CC / 64, BB), dim3(256), 0, stream>>>(x, xT, Wq, Wk, Wv, Wall);
  k_gemm1<<<dim3(640), dim3(256), 0, stream>>>(Wall, xT, bq, bk, bv, qkT, vbuf);
  k_flash<<<dim3(512), dim3(256), 0, stream>>>(qkT, vbuf, x, gamma, out);
}

// Round 10
// 163.196 us; speedup vs baseline: 1.0025x; 1.0025x over previous
//
#include <hip/hip_runtime.h>
#include <stdint.h>

// Problem constants
#define BB 16
#define CC 512
#define CQK 64
#define NN 1024   // H*W = 32*32

typedef __attribute__((ext_vector_type(8))) short bf16x8;
typedef __attribute__((ext_vector_type(4))) short short4v;
typedef __attribute__((ext_vector_type(4))) float f32x4;

static __device__ __forceinline__ unsigned short f2bf(float f) {
  uint32_t u = __float_as_uint(f);
  u += 0x7FFFu + ((u >> 16) & 1u);
  return (unsigned short)(u >> 16);
}

// Async global->LDS, 16B per lane. LDS dest = wave-uniform base + lane*16.
static __device__ __forceinline__ void gll16(const unsigned short* g, unsigned short* l) {
  const __attribute__((address_space(1))) unsigned int* gp =
      reinterpret_cast<const __attribute__((address_space(1))) unsigned int*>(
          reinterpret_cast<uintptr_t>(g));
  __attribute__((address_space(3))) unsigned int* lp =
      reinterpret_cast<__attribute__((address_space(3))) unsigned int*>(
          (unsigned int)reinterpret_cast<uintptr_t>(l));
  __builtin_amdgcn_global_load_lds(gp, lp, 16, 0, 0);
}

// ---------------------------------------------------------------------------
// Kernel 1: transpose x -> xT bf16 + weight pack (R8 body, unchanged).
// grid (N/64=16, C/64=8, B=16), block 256
// ---------------------------------------------------------------------------
__global__ __launch_bounds__(256) void k_prep(
    const float* __restrict__ x, unsigned short* __restrict__ xT,
    const float* __restrict__ Wq, const float* __restrict__ Wk,
    const float* __restrict__ Wv, unsigned short* __restrict__ Wall) {
  __shared__ float tile[64][65];  // 16.6 KB
  int b = blockIdx.z;
  int c0 = blockIdx.y * 64;
  int n0 = blockIdx.x * 64;
  int t = threadIdx.x;

  int flat = ((int)blockIdx.z * gridDim.y + blockIdx.y) * gridDim.x + blockIdx.x;
  if (flat < 320) {
    int e = (flat * 256 + t) * 4;
    int o = e >> 9;
    int c = e & 511;
    const float* src;
    if (o < 64)        src = Wq + (size_t)o * 512;
    else if (o < 128)  src = Wk + (size_t)(o - 64) * 512;
    else               src = Wv + (size_t)(o - 128) * 512;
    float4 v = *(const float4*)(src + c);
    short4v pk;
    pk[0] = (short)f2bf(v.x); pk[1] = (short)f2bf(v.y);
    pk[2] = (short)f2bf(v.z); pk[3] = (short)f2bf(v.w);
    *(short4v*)(Wall + e) = pk;
  }

  int r = t >> 2;        // 0..63 : c-row within tile
  int cg = t & 3;        // 0..3  : 16-float column group
  const float* xp = x + ((size_t)(b * CC + c0 + r)) * NN + n0;
#pragma unroll
  for (int k = 0; k < 4; k++) {
    float4 v = *(const float4*)(xp + k * 16 + cg * 4);
    int cb = k * 16 + cg * 4;
    tile[r][cb + 0] = v.x;
    tile[r][cb + 1] = v.y;
    tile[r][cb + 2] = v.z;
    tile[r][cb + 3] = v.w;
  }
  __syncthreads();

  int n = t >> 2;        // 0..63 : n-row of output
  unsigned short* xq = xT + ((size_t)(b * NN + n0 + n)) * CC + c0 + cg * 16;
  short4v p[4];
#pragma unroll
  for (int q = 0; q < 4; q++) {
#pragma unroll
    for (int j = 0; j < 4; j++) p[q][j] = (short)f2bf(tile[cg * 16 + q * 4 + j][n]);
  }
  *(short4v*)(xq + 0) = p[0];
  *(short4v*)(xq + 4) = p[1];
  *(short4v*)(xq + 8) = p[2];
  *(short4v*)(xq + 12) = p[3];
}

// ---------------------------------------------------------------------------
// Kernel 2: GEMM1 with counted-vmcnt double buffer (R9 body, unchanged).
// ---------------------------------------------------------------------------
__global__ __launch_bounds__(256) void k_gemm1(
    const unsigned short* __restrict__ Wall, const unsigned short* __restrict__ xT,
    const float* __restrict__ bq, const float* __restrict__ bk,
    const float* __restrict__ bv,
    unsigned short* __restrict__ qkT, unsigned short* __restrict__ vbuf) {
  __shared__ __align__(16) unsigned short ldsA[2][128 * 32];
  __shared__ __align__(16) unsigned short ldsB[2][128 * 32];
  int bid = blockIdx.x;
  int swz = (bid & 7) * 80 + (bid >> 3);
  int nx = swz & 7;
  int rest = swz >> 3;
  int oy = rest % 5;
  int b = rest / 5;
  int o0 = oy * 128;
  int n0 = nx * 128;
  int t = threadIdx.x;
  int w = t >> 6, l = t & 63;
  int wm = w & 1, wn = w >> 1;
  int lr = l & 15, lq = l >> 4;

  f32x4 acc[4][4];
#pragma unroll
  for (int i = 0; i < 4; i++)
#pragma unroll
    for (int j = 0; j < 4; j++) acc[i][j] = (f32x4){0.f, 0.f, 0.f, 0.f};

  const unsigned short* Ab = Wall + (size_t)o0 * CC;
  const unsigned short* Bb = xT + ((size_t)b * NN + n0) * CC;
  int srow = t >> 2;
  int skq = (t & 3) * 8;
  int ldsw = (t >> 6) * 512;

#pragma unroll
  for (int p = 0; p < 2; p++) {
    int r = p * 64 + srow;
    gll16(&Ab[(size_t)r * CC + skq], &ldsA[0][p * 2048 + ldsw]);
    gll16(&Bb[(size_t)r * CC + skq], &ldsB[0][p * 2048 + ldsw]);
  }

  for (int s = 0; s < 16; ++s) {
    int cur = s & 1;
    if (s < 15) {
      int kt = (s + 1) * 32;
#pragma unroll
      for (int p = 0; p < 2; p++) {
        int r = p * 64 + srow;
        gll16(&Ab[(size_t)r * CC + kt + skq], &ldsA[cur ^ 1][p * 2048 + ldsw]);
        gll16(&Bb[(size_t)r * CC + kt + skq], &ldsB[cur ^ 1][p * 2048 + ldsw]);
      }
    }
    __builtin_amdgcn_sched_barrier(0);
    if (s < 15) {
      asm volatile("s_waitcnt vmcnt(4)" ::: "memory");
    } else {
      asm volatile("s_waitcnt vmcnt(0)" ::: "memory");
    }
    __builtin_amdgcn_sched_barrier(0);
    __builtin_amdgcn_s_barrier();

    bf16x8 af[4], bfr[4];
#pragma unroll
    for (int i = 0; i < 4; i++)
      af[i] = *(const bf16x8*)(&ldsA[cur][(wm * 64 + i * 16 + lr) * 32 + lq * 8]);
#pragma unroll
    for (int j = 0; j < 4; j++)
      bfr[j] = *(const bf16x8*)(&ldsB[cur][(wn * 64 + j * 16 + lr) * 32 + lq * 8]);
#pragma unroll
    for (int i = 0; i < 4; i++)
#pragma unroll
      for (int j = 0; j < 4; j++)
        acc[i][j] = __builtin_amdgcn_mfma_f32_16x16x32_bf16(af[i], bfr[j], acc[i][j], 0, 0, 0);

    __builtin_amdgcn_s_barrier();
  }

  if (o0 == 0) {
#pragma unroll
    for (int i = 0; i < 4; i++) {
      int ob = wm * 64 + i * 16 + lq * 4;
#pragma unroll
      for (int j = 0; j < 4; j++) {
        int n = n0 + wn * 64 + j * 16 + lr;
        short4v pk;
#pragma unroll
        for (int r = 0; r < 4; r++) {
          int o = ob + r;
          float bias = (o < 64) ? bq[o] : bk[o - 64];
          pk[r] = (short)f2bf(acc[i][j][r] + bias);
        }
        *(short4v*)(&qkT[((size_t)b * NN + n) * 128 + ob]) = pk;
      }
    }
  } else {
#pragma unroll
    for (int i = 0; i < 4; i++) {
#pragma unroll
      for (int r = 0; r < 4; r++) {
        int o = o0 + wm * 64 + i * 16 + lq * 4 + r;
        int c = o - 128;
        float bias = bv[c];
#pragma unroll
        for (int j = 0; j < 4; j++) {
          int n = n0 + wn * 64 + j * 16 + lr;
          vbuf[((size_t)b * CC + c) * NN + n] = f2bf(acc[i][j][r] + bias);
        }
      }
    }
  }
}

// ---------------------------------------------------------------------------
// Kernel 3: one-pass flash, R1 body + P DOUBLE-BUFFER (this round's change):
//   barrier 1 (write-after-read protection on P) is removed by alternating
//   P buffers per chunk -> ONE barrier per chunk (the read-after-write one).
//   Safety: chunk i writes P[i&1]; the last reads of P[i&1] were chunk i-2's
//   PV, separated from this write by chunk i-1's barrier. T5 setprio(1)
//   around the PV MFMA cluster (2 independent blocks/CU = phase diversity).
// ---------------------------------------------------------------------------
#define QT 64
#define MC 64
#define PSTR 72  // ushort units; 144B row stride (16B-aligned, 2-way banks = free)

__global__ __launch_bounds__(256, 2) void k_flash(
    const unsigned short* __restrict__ qkT, const unsigned short* __restrict__ vbuf,
    const float* __restrict__ x, const float* __restrict__ gamma,
    float* __restrict__ out) {
  __shared__ __align__(16) unsigned short P[2][QT * PSTR];  // 18432 B
  __shared__ float red[4 * QT];                             // 1024 B
  __shared__ float fin[QT];                                 // 256 B

  // XCD-aware swizzle: hw block h -> logical id (h%8)*64 + h/8 (512 = 8*64).
  int bid = blockIdx.x;
  int swz = (bid & 7) * 64 + (bid >> 3);
  int ntile = swz & 15;
  int chalf = (swz >> 4) & 1;
  int b = swz >> 5;
  int n0 = ntile * QT;
  int t = threadIdx.x;
  int w = t >> 6, l = t & 63;
  int lr = l & 15, lq = l >> 4;
  const unsigned short* qk = qkT + (size_t)b * NN * 128;
  const unsigned short* Vb = vbuf + ((size_t)b * CC + chalf * 256 + w * 64) * NN;

  // Q fragments (constant over all chunks)
  bf16x8 aq[4][2];
#pragma unroll
  for (int nj = 0; nj < 4; nj++)
#pragma unroll
    for (int ks = 0; ks < 2; ks++)
      aq[nj][ks] = *(const bf16x8*)(&qk[(size_t)(n0 + nj * 16 + lr) * 128 + ks * 32 + lq * 8]);

  f32x4 acc[4][4];  // [ci][nj]
#pragma unroll
  for (int ci = 0; ci < 4; ci++)
#pragma unroll
    for (int nj = 0; nj < 4; nj++) acc[ci][nj] = (f32x4){0.f, 0.f, 0.f, 0.f};
  float sreg[4][4];
#pragma unroll
  for (int nj = 0; nj < 4; nj++)
#pragma unroll
    for (int r = 0; r < 4; r++) sreg[nj][r] = 0.f;

  // Prologue: scores+exp for chunk 0
  float ev[4][4];
  {
    int mrow = w * 16 + lr;  // m0 = 0
    bf16x8 kf0 = *(const bf16x8*)(&qk[(size_t)mrow * 128 + 64 + lq * 8]);
    bf16x8 kf1 = *(const bf16x8*)(&qk[(size_t)mrow * 128 + 96 + lq * 8]);
#pragma unroll
    for (int nj = 0; nj < 4; nj++) {
      f32x4 s = (f32x4){0.f, 0.f, 0.f, 0.f};
      s = __builtin_amdgcn_mfma_f32_16x16x32_bf16(aq[nj][0], kf0, s, 0, 0, 0);
      s = __builtin_amdgcn_mfma_f32_16x16x32_bf16(aq[nj][1], kf1, s, 0, 0, 0);
#pragma unroll
      for (int r = 0; r < 4; r++) {
        float e = __expf(s[r]);
        ev[nj][r] = e;
        sreg[nj][r] += e;
      }
    }
  }

  int pb = 0;
  for (int m0 = 0; m0 < NN; m0 += MC, pb ^= 1) {
    // Prefetch V fragments for ks=0 of this chunk.
    bf16x8 af0[4];
#pragma unroll
    for (int ci = 0; ci < 4; ci++)
      af0[ci] = *(const bf16x8*)(&Vb[(size_t)(ci * 16 + lr) * NN + m0 + lq * 8]);

    // Prefetch next-chunk K fragments early.
    bf16x8 kf0n, kf1n;
    if (m0 + MC < NN) {
      int mrow = m0 + MC + w * 16 + lr;
      kf0n = *(const bf16x8*)(&qk[(size_t)mrow * 128 + 64 + lq * 8]);
      kf1n = *(const bf16x8*)(&qk[(size_t)mrow * 128 + 96 + lq * 8]);
    }

    // Write this chunk's P into buffer pb — no barrier needed: last reads
    // of P[pb] (chunk m0-2*MC) are separated by the previous chunk's barrier.
#pragma unroll
    for (int nj = 0; nj < 4; nj++)
#pragma unroll
      for (int r = 0; r < 4; r++)
        P[pb][(nj * 16 + lq * 4 + r) * PSTR + w * 16 + lr] = f2bf(ev[nj][r]);

    // Compute scores+exp for NEXT chunk while P settles.
    if (m0 + MC < NN) {
#pragma unroll
      for (int nj = 0; nj < 4; nj++) {
        f32x4 s = (f32x4){0.f, 0.f, 0.f, 0.f};
        s = __builtin_amdgcn_mfma_f32_16x16x32_bf16(aq[nj][0], kf0n, s, 0, 0, 0);
        s = __builtin_amdgcn_mfma_f32_16x16x32_bf16(aq[nj][1], kf1n, s, 0, 0, 0);
#pragma unroll
        for (int r = 0; r < 4; r++) {
          float e = __expf(s[r]);
          ev[nj][r] = e;
          sreg[nj][r] += e;
        }
      }
    }
    __syncthreads();  // P[pb] ready (read-after-write)

    // Prefetch V for ks=1 (latency hidden by ks=0 MFMAs).
    bf16x8 af1[4];
#pragma unroll
    for (int ci = 0; ci < 4; ci++)
      af1[ci] = *(const bf16x8*)(&Vb[(size_t)(ci * 16 + lr) * NN + m0 + 32 + lq * 8]);

    __builtin_amdgcn_s_setprio(1);
    // PV ks=0
#pragma unroll
    for (int nj = 0; nj < 4; nj++) {
      bf16x8 pf = *(const bf16x8*)(&P[pb][(nj * 16 + lr) * PSTR + lq * 8]);
#pragma unroll
      for (int ci = 0; ci < 4; ci++)
        acc[ci][nj] = __builtin_amdgcn_mfma_f32_16x16x32_bf16(af0[ci], pf, acc[ci][nj], 0, 0, 0);
    }
    // PV ks=1
#pragma unroll
    for (int nj = 0; nj < 4; nj++) {
      bf16x8 pf = *(const bf16x8*)(&P[pb][(nj * 16 + lr) * PSTR + 32 + lq * 8]);
#pragma unroll
      for (int ci = 0; ci < 4; ci++)
        acc[ci][nj] = __builtin_amdgcn_mfma_f32_16x16x32_bf16(af1[ci], pf, acc[ci][nj], 0, 0, 0);
    }
    __builtin_amdgcn_s_setprio(0);
  }

  // ---- final row sums (across 16 lr lanes, then 4 waves) ----
#pragma unroll
  for (int nj = 0; nj < 4; nj++)
#pragma unroll
    for (int r = 0; r < 4; r++) {
#pragma unroll
      for (int d = 1; d < 16; d <<= 1) sreg[nj][r] += __shfl_xor(sreg[nj][r], d, 64);
    }
  __syncthreads();
  if (lr == 0) {
#pragma unroll
    for (int nj = 0; nj < 4; nj++)
#pragma unroll
      for (int r = 0; r < 4; r++) red[w * QT + nj * 16 + lq * 4 + r] = sreg[nj][r];
  }
  __syncthreads();
  if (t < QT) {
    float ssum = red[t] + red[QT + t] + red[2 * QT + t] + red[3 * QT + t];
    fin[t] = ssum;
  }
  __syncthreads();

  float invL[4];
#pragma unroll
  for (int nj = 0; nj < 4; nj++) invL[nj] = 1.0f / fin[nj * 16 + lr];
  float g = gamma[0];
#pragma unroll
  for (int ci = 0; ci < 4; ci++) {
#pragma unroll
    for (int r = 0; r < 4; r++) {
      int c = chalf * 256 + w * 64 + ci * 16 + lq * 4 + r;
#pragma unroll
      for (int nj = 0; nj < 4; nj++) {
        size_t idx = ((size_t)b * CC + c) * NN + n0 + nj * 16 + lr;
        out[idx] = g * acc[ci][nj][r] * invL[nj] + x[idx];
      }
    }
  }
}

// ---------------------------------------------------------------------------
extern "C" void kernel_launch(void* const* d_in, const int* in_sizes, int n_in,
                              void* d_out, int out_size, void* d_ws, size_t ws_size,
                              hipStream_t stream) {
  (void)in_sizes; (void)n_in; (void)out_size; (void)ws_size;
  const float* x     = (const float*)d_in[0];
  const float* Wq    = (const float*)d_in[1];
  const float* bq    = (const float*)d_in[2];
  const float* Wk    = (const float*)d_in[3];
  const float* bk    = (const float*)d_in[4];
  const float* Wv    = (const float*)d_in[5];
  const float* bv    = (const float*)d_in[6];
  const float* gamma = (const float*)d_in[7];
  float* out = (float*)d_out;

  char* ws = (char*)d_ws;
  unsigned short* Wall = (unsigned short*)(ws);                       // 655,360 B
  unsigned short* xT   = (unsigned short*)(ws + 655360);              // 16,777,216 B
  unsigned short* qkT  = (unsigned short*)(ws + 655360 + 16777216);   // 4,194,304 B
  unsigned short* vbuf = (unsigned short*)(ws + 655360 + 16777216 + 4194304);  // 16,777,216 B
  // total ~38.4 MB

  k_prep<<<dim3(NN / 64, CC / 64, BB), dim3(256), 0, stream>>>(x, xT, Wq, Wk, Wv, Wall);
  k_gemm1<<<dim3(640), dim3(256), 0, stream>>>(Wall, xT, bq, bk, bv, qkT, vbuf);
  k_flash<<<dim3(512), dim3(256), 0, stream>>>(qkT, vbuf, x, gamma, out);
}

// Round 11
// 153.928 us; speedup vs baseline: 1.0629x; 1.0602x over previous
//
#include <hip/hip_runtime.h>
#include <stdint.h>

// Problem constants
#define BB 16
#define CC 512
#define CQK 64
#define NN 1024   // H*W = 32*32

typedef __attribute__((ext_vector_type(8))) short bf16x8;
typedef __attribute__((ext_vector_type(4))) short short4v;
typedef __attribute__((ext_vector_type(4))) float f32x4;

static __device__ __forceinline__ unsigned short f2bf(float f) {
  uint32_t u = __float_as_uint(f);
  u += 0x7FFFu + ((u >> 16) & 1u);
  return (unsigned short)(u >> 16);
}

// Async global->LDS, 16B per lane. LDS dest = wave-uniform base + lane*16.
static __device__ __forceinline__ void gll16(const unsigned short* g, unsigned short* l) {
  const __attribute__((address_space(1))) unsigned int* gp =
      reinterpret_cast<const __attribute__((address_space(1))) unsigned int*>(
          reinterpret_cast<uintptr_t>(g));
  __attribute__((address_space(3))) unsigned int* lp =
      reinterpret_cast<__attribute__((address_space(3))) unsigned int*>(
          (unsigned int)reinterpret_cast<uintptr_t>(l));
  __builtin_amdgcn_global_load_lds(gp, lp, 16, 0, 0);
}

// ---------------------------------------------------------------------------
// Kernel 1: transpose x -> xT bf16 + weight pack (R8 body, unchanged).
// grid (N/64=16, C/64=8, B=16), block 256
// ---------------------------------------------------------------------------
__global__ __launch_bounds__(256) void k_prep(
    const float* __restrict__ x, unsigned short* __restrict__ xT,
    const float* __restrict__ Wq, const float* __restrict__ Wk,
    const float* __restrict__ Wv, unsigned short* __restrict__ Wall) {
  __shared__ float tile[64][65];  // 16.6 KB
  int b = blockIdx.z;
  int c0 = blockIdx.y * 64;
  int n0 = blockIdx.x * 64;
  int t = threadIdx.x;

  int flat = ((int)blockIdx.z * gridDim.y + blockIdx.y) * gridDim.x + blockIdx.x;
  if (flat < 320) {
    int e = (flat * 256 + t) * 4;
    int o = e >> 9;
    int c = e & 511;
    const float* src;
    if (o < 64)        src = Wq + (size_t)o * 512;
    else if (o < 128)  src = Wk + (size_t)(o - 64) * 512;
    else               src = Wv + (size_t)(o - 128) * 512;
    float4 v = *(const float4*)(src + c);
    short4v pk;
    pk[0] = (short)f2bf(v.x); pk[1] = (short)f2bf(v.y);
    pk[2] = (short)f2bf(v.z); pk[3] = (short)f2bf(v.w);
    *(short4v*)(Wall + e) = pk;
  }

  int r = t >> 2;        // 0..63 : c-row within tile
  int cg = t & 3;        // 0..3  : 16-float column group
  const float* xp = x + ((size_t)(b * CC + c0 + r)) * NN + n0;
#pragma unroll
  for (int k = 0; k < 4; k++) {
    float4 v = *(const float4*)(xp + k * 16 + cg * 4);
    int cb = k * 16 + cg * 4;
    tile[r][cb + 0] = v.x;
    tile[r][cb + 1] = v.y;
    tile[r][cb + 2] = v.z;
    tile[r][cb + 3] = v.w;
  }
  __syncthreads();

  int n = t >> 2;        // 0..63 : n-row of output
  unsigned short* xq = xT + ((size_t)(b * NN + n0 + n)) * CC + c0 + cg * 16;
  short4v p[4];
#pragma unroll
  for (int q = 0; q < 4; q++) {
#pragma unroll
    for (int j = 0; j < 4; j++) p[q][j] = (short)f2bf(tile[cg * 16 + q * 4 + j][n]);
  }
  *(short4v*)(xq + 0) = p[0];
  *(short4v*)(xq + 4) = p[1];
  *(short4v*)(xq + 8) = p[2];
  *(short4v*)(xq + 12) = p[3];
}

// ---------------------------------------------------------------------------
// Kernel 2: GEMM1 with counted-vmcnt double buffer (R9 body, unchanged).
// ---------------------------------------------------------------------------
__global__ __launch_bounds__(256) void k_gemm1(
    const unsigned short* __restrict__ Wall, const unsigned short* __restrict__ xT,
    const float* __restrict__ bq, const float* __restrict__ bk,
    const float* __restrict__ bv,
    unsigned short* __restrict__ qkT, unsigned short* __restrict__ vbuf) {
  __shared__ __align__(16) unsigned short ldsA[2][128 * 32];
  __shared__ __align__(16) unsigned short ldsB[2][128 * 32];
  int bid = blockIdx.x;
  int swz = (bid & 7) * 80 + (bid >> 3);
  int nx = swz & 7;
  int rest = swz >> 3;
  int oy = rest % 5;
  int b = rest / 5;
  int o0 = oy * 128;
  int n0 = nx * 128;
  int t = threadIdx.x;
  int w = t >> 6, l = t & 63;
  int wm = w & 1, wn = w >> 1;
  int lr = l & 15, lq = l >> 4;

  f32x4 acc[4][4];
#pragma unroll
  for (int i = 0; i < 4; i++)
#pragma unroll
    for (int j = 0; j < 4; j++) acc[i][j] = (f32x4){0.f, 0.f, 0.f, 0.f};

  const unsigned short* Ab = Wall + (size_t)o0 * CC;
  const unsigned short* Bb = xT + ((size_t)b * NN + n0) * CC;
  int srow = t >> 2;
  int skq = (t & 3) * 8;
  int ldsw = (t >> 6) * 512;

#pragma unroll
  for (int p = 0; p < 2; p++) {
    int r = p * 64 + srow;
    gll16(&Ab[(size_t)r * CC + skq], &ldsA[0][p * 2048 + ldsw]);
    gll16(&Bb[(size_t)r * CC + skq], &ldsB[0][p * 2048 + ldsw]);
  }

  for (int s = 0; s < 16; ++s) {
    int cur = s & 1;
    if (s < 15) {
      int kt = (s + 1) * 32;
#pragma unroll
      for (int p = 0; p < 2; p++) {
        int r = p * 64 + srow;
        gll16(&Ab[(size_t)r * CC + kt + skq], &ldsA[cur ^ 1][p * 2048 + ldsw]);
        gll16(&Bb[(size_t)r * CC + kt + skq], &ldsB[cur ^ 1][p * 2048 + ldsw]);
      }
    }
    __builtin_amdgcn_sched_barrier(0);
    if (s < 15) {
      asm volatile("s_waitcnt vmcnt(4)" ::: "memory");
    } else {
      asm volatile("s_waitcnt vmcnt(0)" ::: "memory");
    }
    __builtin_amdgcn_sched_barrier(0);
    __builtin_amdgcn_s_barrier();

    bf16x8 af[4], bfr[4];
#pragma unroll
    for (int i = 0; i < 4; i++)
      af[i] = *(const bf16x8*)(&ldsA[cur][(wm * 64 + i * 16 + lr) * 32 + lq * 8]);
#pragma unroll
    for (int j = 0; j < 4; j++)
      bfr[j] = *(const bf16x8*)(&ldsB[cur][(wn * 64 + j * 16 + lr) * 32 + lq * 8]);
#pragma unroll
    for (int i = 0; i < 4; i++)
#pragma unroll
      for (int j = 0; j < 4; j++)
        acc[i][j] = __builtin_amdgcn_mfma_f32_16x16x32_bf16(af[i], bfr[j], acc[i][j], 0, 0, 0);

    __builtin_amdgcn_s_barrier();
  }

  if (o0 == 0) {
#pragma unroll
    for (int i = 0; i < 4; i++) {
      int ob = wm * 64 + i * 16 + lq * 4;
#pragma unroll
      for (int j = 0; j < 4; j++) {
        int n = n0 + wn * 64 + j * 16 + lr;
        short4v pk;
#pragma unroll
        for (int r = 0; r < 4; r++) {
          int o = ob + r;
          float bias = (o < 64) ? bq[o] : bk[o - 64];
          pk[r] = (short)f2bf(acc[i][j][r] + bias);
        }
        *(short4v*)(&qkT[((size_t)b * NN + n) * 128 + ob]) = pk;
      }
    }
  } else {
#pragma unroll
    for (int i = 0; i < 4; i++) {
#pragma unroll
      for (int r = 0; r < 4; r++) {
        int o = o0 + wm * 64 + i * 16 + lq * 4 + r;
        int c = o - 128;
        float bias = bv[c];
#pragma unroll
        for (int j = 0; j < 4; j++) {
          int n = n0 + wn * 64 + j * 16 + lr;
          vbuf[((size_t)b * CC + c) * NN + n] = f2bf(acc[i][j][r] + bias);
        }
      }
    }
  }
}

// ---------------------------------------------------------------------------
// Kernel 3: flash with V STAGED THROUGH LDS (this round's single change).
//   Old V path: 8 bf16x8 register loads/wave/chunk, each touching 16 rows at
//   2KB stride = 128 scattered L2 lines per wave per chunk -> serialized
//   L2-latency epochs (the 8000cy/chunk wall no other variant moved).
//   New: V 64-key tile (256ch x 64k = 32KB) staged to LDS via global_load_lds
//   (coalesced 128B row segments), double-buffered, counted vmcnt(8) across
//   a raw s_barrier (T4: stage stays in flight; barrier1 waits lgkm only).
//   XOR-swizzle pair (m173: pre-swizzled global source + swizzled ds_read;
//   involution p ^ ((ch&7)<<3) within each 64-ushort row) keeps reads ~free
//   of bank conflicts. LDS 76KB -> still 2 blocks/CU.
// ---------------------------------------------------------------------------
#define QT 64
#define MC 64
#define PSTR 72  // ushort units; 144B row stride (16B-aligned, 2-way banks = free)

__global__ __launch_bounds__(256, 2) void k_flash(
    const unsigned short* __restrict__ qkT, const unsigned short* __restrict__ vbuf,
    const float* __restrict__ x, const float* __restrict__ gamma,
    float* __restrict__ out) {
  __shared__ __align__(16) unsigned short Vl[2][256 * 64];  // 65536 B
  __shared__ __align__(16) unsigned short P[QT * PSTR];     // 9216 B
  __shared__ float red[4 * QT];                             // 1024 B
  __shared__ float fin[QT];                                 // 256 B

  // XCD-aware swizzle: hw block h -> logical id (h%8)*64 + h/8 (512 = 8*64).
  int bid = blockIdx.x;
  int swz = (bid & 7) * 64 + (bid >> 3);
  int ntile = swz & 15;
  int chalf = (swz >> 4) & 1;
  int b = swz >> 5;
  int n0 = ntile * QT;
  int t = threadIdx.x;
  int w = t >> 6, l = t & 63;
  int lr = l & 15, lq = l >> 4;
  const unsigned short* qk = qkT + (size_t)b * NN * 128;
  const unsigned short* Vg = vbuf + ((size_t)b * CC + chalf * 256) * NN;

  // --- V staging constants ---
  // Stage round g (0..7): wave w writes LDS ushorts [g*2048 + w*512, +512)
  // linearly (lane*16B). Lane covers ch = g*32 + (t>>3), in-row ushorts
  // [(t&7)*8, +8). Global source pre-swizzled: koff = ((t&7)*8)^((ch&7)<<3)
  // so that LDS[ch][p] = V[ch][m0 + (p ^ ((ch&7)<<3))]  (involution).
  int chb = t >> 3;                              // 0..31
  int koff = ((t & 7) * 8) ^ ((chb & 7) << 3);   // ushort offset in 64-key window
  int sbase = w * 512;                           // wave-uniform LDS lane-0 offset

  // Q fragments (constant over all chunks)
  bf16x8 aq[4][2];
#pragma unroll
  for (int nj = 0; nj < 4; nj++)
#pragma unroll
    for (int ks = 0; ks < 2; ks++)
      aq[nj][ks] = *(const bf16x8*)(&qk[(size_t)(n0 + nj * 16 + lr) * 128 + ks * 32 + lq * 8]);

  f32x4 acc[4][4];  // [ci][nj]
#pragma unroll
  for (int ci = 0; ci < 4; ci++)
#pragma unroll
    for (int nj = 0; nj < 4; nj++) acc[ci][nj] = (f32x4){0.f, 0.f, 0.f, 0.f};
  float sreg[4][4];
#pragma unroll
  for (int nj = 0; nj < 4; nj++)
#pragma unroll
    for (int r = 0; r < 4; r++) sreg[nj][r] = 0.f;

  // Prologue: stage V(chunk 0) into buf 0.
#pragma unroll
  for (int g = 0; g < 8; g++)
    gll16(&Vg[(size_t)(g * 32 + chb) * NN + koff], &Vl[0][g * 2048 + sbase]);

  // Prologue: scores+exp for chunk 0.
  float ev[4][4];
  {
    int mrow = w * 16 + lr;  // m0 = 0
    bf16x8 kf0 = *(const bf16x8*)(&qk[(size_t)mrow * 128 + 64 + lq * 8]);
    bf16x8 kf1 = *(const bf16x8*)(&qk[(size_t)mrow * 128 + 96 + lq * 8]);
#pragma unroll
    for (int nj = 0; nj < 4; nj++) {
      f32x4 s = (f32x4){0.f, 0.f, 0.f, 0.f};
      s = __builtin_amdgcn_mfma_f32_16x16x32_bf16(aq[nj][0], kf0, s, 0, 0, 0);
      s = __builtin_amdgcn_mfma_f32_16x16x32_bf16(aq[nj][1], kf1, s, 0, 0, 0);
#pragma unroll
      for (int r = 0; r < 4; r++) {
        float e = __expf(s[r]);
        ev[nj][r] = e;
        sreg[nj][r] += e;
      }
    }
  }

  int cur = 0;
  for (int m0 = 0; m0 < NN; m0 += MC, cur ^= 1) {
    bool hn = (m0 + MC < NN);
    // Next-chunk K fragments (issued before barrier1, consumed after; they
    // ride across the barrier in flight).
    bf16x8 kf0n, kf1n;
    if (hn) {
      int mrow = m0 + MC + w * 16 + lr;
      kf0n = *(const bf16x8*)(&qk[(size_t)mrow * 128 + 64 + lq * 8]);
      kf1n = *(const bf16x8*)(&qk[(size_t)mrow * 128 + 96 + lq * 8]);
    }

    // barrier1: prev chunk's PV reads (P and Vl[cur^1]) complete.
    // lgkm-only wait: K loads + in-flight stage do NOT drain here.
    asm volatile("s_waitcnt lgkmcnt(0)" ::: "memory");
    __builtin_amdgcn_sched_barrier(0);
    __builtin_amdgcn_s_barrier();

    // Stage V(next chunk) into Vl[cur^1] (WAR-safe: its last readers were
    // chunk m0-MC's PV, upstream of barrier1).
    if (hn) {
#pragma unroll
      for (int g = 0; g < 8; g++)
        gll16(&Vg[(size_t)(g * 32 + chb) * NN + (m0 + MC) + koff],
              &Vl[cur ^ 1][g * 2048 + sbase]);
    }

    // P-write for this chunk.
#pragma unroll
    for (int nj = 0; nj < 4; nj++)
#pragma unroll
      for (int r = 0; r < 4; r++)
        P[(nj * 16 + lq * 4 + r) * PSTR + w * 16 + lr] = f2bf(ev[nj][r]);

    // Scores+exp for NEXT chunk while P settles.
    if (hn) {
#pragma unroll
      for (int nj = 0; nj < 4; nj++) {
        f32x4 s = (f32x4){0.f, 0.f, 0.f, 0.f};
        s = __builtin_amdgcn_mfma_f32_16x16x32_bf16(aq[nj][0], kf0n, s, 0, 0, 0);
        s = __builtin_amdgcn_mfma_f32_16x16x32_bf16(aq[nj][1], kf1n, s, 0, 0, 0);
#pragma unroll
        for (int r = 0; r < 4; r++) {
          float e = __expf(s[r]);
          ev[nj][r] = e;
          sreg[nj][r] += e;
        }
      }
    }

    // barrier2: P visible + Vl[cur] (staged LAST chunk = oldest vmem) landed.
    // Counted vmcnt: the 8 just-issued stage loads stay in flight.
    if (hn) {
      asm volatile("s_waitcnt vmcnt(8) lgkmcnt(0)" ::: "memory");
    } else {
      asm volatile("s_waitcnt vmcnt(0) lgkmcnt(0)" ::: "memory");
    }
    __builtin_amdgcn_sched_barrier(0);
    __builtin_amdgcn_s_barrier();

    // PV: V fragments from LDS (swizzled read), P fragments from LDS.
#pragma unroll
    for (int ks = 0; ks < 2; ks++) {
      bf16x8 vf[4];
#pragma unroll
      for (int ci = 0; ci < 4; ci++) {
        int row = w * 64 + ci * 16 + lr;
        int idx = row * 64 + (((ks * 32 + lq * 8)) ^ ((lr & 7) << 3));
        vf[ci] = *(const bf16x8*)(&Vl[cur][idx]);
      }
#pragma unroll
      for (int nj = 0; nj < 4; nj++) {
        bf16x8 pf = *(const bf16x8*)(&P[(nj * 16 + lr) * PSTR + ks * 32 + lq * 8]);
#pragma unroll
        for (int ci = 0; ci < 4; ci++)
          acc[ci][nj] = __builtin_amdgcn_mfma_f32_16x16x32_bf16(vf[ci], pf, acc[ci][nj], 0, 0, 0);
      }
    }
  }

  // ---- final row sums (across 16 lr lanes, then 4 waves) ----
#pragma unroll
  for (int nj = 0; nj < 4; nj++)
#pragma unroll
    for (int r = 0; r < 4; r++) {
#pragma unroll
      for (int d = 1; d < 16; d <<= 1) sreg[nj][r] += __shfl_xor(sreg[nj][r], d, 64);
    }
  __syncthreads();
  if (lr == 0) {
#pragma unroll
    for (int nj = 0; nj < 4; nj++)
#pragma unroll
      for (int r = 0; r < 4; r++) red[w * QT + nj * 16 + lq * 4 + r] = sreg[nj][r];
  }
  __syncthreads();
  if (t < QT) {
    float ssum = red[t] + red[QT + t] + red[2 * QT + t] + red[3 * QT + t];
    fin[t] = ssum;
  }
  __syncthreads();

  float invL[4];
#pragma unroll
  for (int nj = 0; nj < 4; nj++) invL[nj] = 1.0f / fin[nj * 16 + lr];
  float g = gamma[0];
#pragma unroll
  for (int ci = 0; ci < 4; ci++) {
#pragma unroll
    for (int r = 0; r < 4; r++) {
      int c = chalf * 256 + w * 64 + ci * 16 + lq * 4 + r;
#pragma unroll
      for (int nj = 0; nj < 4; nj++) {
        size_t idx = ((size_t)b * CC + c) * NN + n0 + nj * 16 + lr;
        out[idx] = g * acc[ci][nj][r] * invL[nj] + x[idx];
      }
    }
  }
}

// ---------------------------------------------------------------------------
extern "C" void kernel_launch(void* const* d_in, const int* in_sizes, int n_in,
                              void* d_out, int out_size, void* d_ws, size_t ws_size,
                              hipStream_t stream) {
  (void)in_sizes; (void)n_in; (void)out_size; (void)ws_size;
  const float* x     = (const float*)d_in[0];
  const float* Wq    = (const float*)d_in[1];
  const float* bq    = (const float*)d_in[2];
  const float* Wk    = (const float*)d_in[3];
  const float* bk    = (const float*)d_in[4];
  const float* Wv    = (const float*)d_in[5];
  const float* bv    = (const float*)d_in[6];
  const float* gamma = (const float*)d_in[7];
  float* out = (float*)d_out;

  char* ws = (char*)d_ws;
  unsigned short* Wall = (unsigned short*)(ws);                       // 655,360 B
  unsigned short* xT   = (unsigned short*)(ws + 655360);              // 16,777,216 B
  unsigned short* qkT  = (unsigned short*)(ws + 655360 + 16777216);   // 4,194,304 B
  unsigned short* vbuf = (unsigned short*)(ws + 655360 + 16777216 + 4194304);  // 16,777,216 B
  // total ~38.4 MB

  k_prep<<<dim3(NN / 64, CC / 64, BB), dim3(256), 0, stream>>>(x, xT, Wq, Wk, Wv, Wall);
  k_gemm1<<<dim3(640), dim3(256), 0, stream>>>(Wall, xT, bq, bk, bv, qkT, vbuf);
  k_flash<<<dim3(512), dim3(256), 0, stream>>>(qkT, vbuf, x, gamma, out);
}

// Round 12
// 153.249 us; speedup vs baseline: 1.0676x; 1.0044x over previous
//
#include <hip/hip_runtime.h>
#include <stdint.h>

// Problem constants
#define BB 16
#define CC 512
#define CQK 64
#define NN 1024   // H*W = 32*32

typedef __attribute__((ext_vector_type(8))) short bf16x8;
typedef __attribute__((ext_vector_type(4))) short short4v;
typedef __attribute__((ext_vector_type(4))) float f32x4;

static __device__ __forceinline__ unsigned short f2bf(float f) {
  uint32_t u = __float_as_uint(f);
  u += 0x7FFFu + ((u >> 16) & 1u);
  return (unsigned short)(u >> 16);
}

// Async global->LDS, 16B per lane. LDS dest = wave-uniform base + lane*16.
static __device__ __forceinline__ void gll16(const unsigned short* g, unsigned short* l) {
  const __attribute__((address_space(1))) unsigned int* gp =
      reinterpret_cast<const __attribute__((address_space(1))) unsigned int*>(
          reinterpret_cast<uintptr_t>(g));
  __attribute__((address_space(3))) unsigned int* lp =
      reinterpret_cast<__attribute__((address_space(3))) unsigned int*>(
          (unsigned int)reinterpret_cast<uintptr_t>(l));
  __builtin_amdgcn_global_load_lds(gp, lp, 16, 0, 0);
}

// ---------------------------------------------------------------------------
// Kernel 1: transpose x -> xT bf16 + weight pack (R8 body, unchanged).
// grid (N/64=16, C/64=8, B=16), block 256
// ---------------------------------------------------------------------------
__global__ __launch_bounds__(256) void k_prep(
    const float* __restrict__ x, unsigned short* __restrict__ xT,
    const float* __restrict__ Wq, const float* __restrict__ Wk,
    const float* __restrict__ Wv, unsigned short* __restrict__ Wall) {
  __shared__ float tile[64][65];  // 16.6 KB
  int b = blockIdx.z;
  int c0 = blockIdx.y * 64;
  int n0 = blockIdx.x * 64;
  int t = threadIdx.x;

  int flat = ((int)blockIdx.z * gridDim.y + blockIdx.y) * gridDim.x + blockIdx.x;
  if (flat < 320) {
    int e = (flat * 256 + t) * 4;
    int o = e >> 9;
    int c = e & 511;
    const float* src;
    if (o < 64)        src = Wq + (size_t)o * 512;
    else if (o < 128)  src = Wk + (size_t)(o - 64) * 512;
    else               src = Wv + (size_t)(o - 128) * 512;
    float4 v = *(const float4*)(src + c);
    short4v pk;
    pk[0] = (short)f2bf(v.x); pk[1] = (short)f2bf(v.y);
    pk[2] = (short)f2bf(v.z); pk[3] = (short)f2bf(v.w);
    *(short4v*)(Wall + e) = pk;
  }

  int r = t >> 2;        // 0..63 : c-row within tile
  int cg = t & 3;        // 0..3  : 16-float column group
  const float* xp = x + ((size_t)(b * CC + c0 + r)) * NN + n0;
#pragma unroll
  for (int k = 0; k < 4; k++) {
    float4 v = *(const float4*)(xp + k * 16 + cg * 4);
    int cb = k * 16 + cg * 4;
    tile[r][cb + 0] = v.x;
    tile[r][cb + 1] = v.y;
    tile[r][cb + 2] = v.z;
    tile[r][cb + 3] = v.w;
  }
  __syncthreads();

  int n = t >> 2;        // 0..63 : n-row of output
  unsigned short* xq = xT + ((size_t)(b * NN + n0 + n)) * CC + c0 + cg * 16;
  short4v p[4];
#pragma unroll
  for (int q = 0; q < 4; q++) {
#pragma unroll
    for (int j = 0; j < 4; j++) p[q][j] = (short)f2bf(tile[cg * 16 + q * 4 + j][n]);
  }
  *(short4v*)(xq + 0) = p[0];
  *(short4v*)(xq + 4) = p[1];
  *(short4v*)(xq + 8) = p[2];
  *(short4v*)(xq + 12) = p[3];
}

// ---------------------------------------------------------------------------
// Kernel 2: GEMM1 (R9 counted-vmcnt body). THIS ROUND: Q/K outputs split:
//   Q (o<64)  -> Qb[b][n][64]        (row layout; flash reads it only 8x/block)
//   K (o in [64,128)) -> Kp permuted [key/16][d/8][key%16][d%8] so flash's
//   per-chunk K-fragment loads become ONE fully-coalesced 2KB segment/wave
//   (was: 16 rows x 256B stride = 16 L2 lines per load — same scatter disease
//   the R11 V-fix removed, at 1/4 volume).
//   V path unchanged.
// ---------------------------------------------------------------------------
__global__ __launch_bounds__(256) void k_gemm1(
    const unsigned short* __restrict__ Wall, const unsigned short* __restrict__ xT,
    const float* __restrict__ bq, const float* __restrict__ bk,
    const float* __restrict__ bv,
    unsigned short* __restrict__ Qb, unsigned short* __restrict__ Kp,
    unsigned short* __restrict__ vbuf) {
  __shared__ __align__(16) unsigned short ldsA[2][128 * 32];
  __shared__ __align__(16) unsigned short ldsB[2][128 * 32];
  int bid = blockIdx.x;
  int swz = (bid & 7) * 80 + (bid >> 3);
  int nx = swz & 7;
  int rest = swz >> 3;
  int oy = rest % 5;
  int b = rest / 5;
  int o0 = oy * 128;
  int n0 = nx * 128;
  int t = threadIdx.x;
  int w = t >> 6, l = t & 63;
  int wm = w & 1, wn = w >> 1;
  int lr = l & 15, lq = l >> 4;

  f32x4 acc[4][4];
#pragma unroll
  for (int i = 0; i < 4; i++)
#pragma unroll
    for (int j = 0; j < 4; j++) acc[i][j] = (f32x4){0.f, 0.f, 0.f, 0.f};

  const unsigned short* Ab = Wall + (size_t)o0 * CC;
  const unsigned short* Bb = xT + ((size_t)b * NN + n0) * CC;
  int srow = t >> 2;
  int skq = (t & 3) * 8;
  int ldsw = (t >> 6) * 512;

#pragma unroll
  for (int p = 0; p < 2; p++) {
    int r = p * 64 + srow;
    gll16(&Ab[(size_t)r * CC + skq], &ldsA[0][p * 2048 + ldsw]);
    gll16(&Bb[(size_t)r * CC + skq], &ldsB[0][p * 2048 + ldsw]);
  }

  for (int s = 0; s < 16; ++s) {
    int cur = s & 1;
    if (s < 15) {
      int kt = (s + 1) * 32;
#pragma unroll
      for (int p = 0; p < 2; p++) {
        int r = p * 64 + srow;
        gll16(&Ab[(size_t)r * CC + kt + skq], &ldsA[cur ^ 1][p * 2048 + ldsw]);
        gll16(&Bb[(size_t)r * CC + kt + skq], &ldsB[cur ^ 1][p * 2048 + ldsw]);
      }
    }
    __builtin_amdgcn_sched_barrier(0);
    if (s < 15) {
      asm volatile("s_waitcnt vmcnt(4)" ::: "memory");
    } else {
      asm volatile("s_waitcnt vmcnt(0)" ::: "memory");
    }
    __builtin_amdgcn_sched_barrier(0);
    __builtin_amdgcn_s_barrier();

    bf16x8 af[4], bfr[4];
#pragma unroll
    for (int i = 0; i < 4; i++)
      af[i] = *(const bf16x8*)(&ldsA[cur][(wm * 64 + i * 16 + lr) * 32 + lq * 8]);
#pragma unroll
    for (int j = 0; j < 4; j++)
      bfr[j] = *(const bf16x8*)(&ldsB[cur][(wn * 64 + j * 16 + lr) * 32 + lq * 8]);
#pragma unroll
    for (int i = 0; i < 4; i++)
#pragma unroll
      for (int j = 0; j < 4; j++)
        acc[i][j] = __builtin_amdgcn_mfma_f32_16x16x32_bf16(af[i], bfr[j], acc[i][j], 0, 0, 0);

    __builtin_amdgcn_s_barrier();
  }

  if (o0 == 0) {
    if (wm == 0) {
      // ---- Q half: ob = i*16+lq*4 in [0,64) -> Qb[b][n][64]
#pragma unroll
      for (int i = 0; i < 4; i++) {
        int ob = i * 16 + lq * 4;
#pragma unroll
        for (int j = 0; j < 4; j++) {
          int n = n0 + wn * 64 + j * 16 + lr;
          short4v pk;
#pragma unroll
          for (int r = 0; r < 4; r++) pk[r] = (short)f2bf(acc[i][j][r] + bq[ob + r]);
          *(short4v*)(&Qb[((size_t)b * NN + n) * 64 + ob]) = pk;
        }
      }
    } else {
      // ---- K half: d = i*16+lq*4+r, key = n ->
      //      Kp[b][key>>4][d>>3][key&15][d&7]  (group=1024 ushorts)
#pragma unroll
      for (int i = 0; i < 4; i++) {
#pragma unroll
        for (int j = 0; j < 4; j++) {
          int n = n0 + wn * 64 + j * 16 + lr;
          short4v pk;
#pragma unroll
          for (int r = 0; r < 4; r++) pk[r] = (short)f2bf(acc[i][j][r] + bk[i * 16 + lq * 4 + r]);
          size_t idx = (size_t)b * 65536 + (size_t)(n >> 4) * 1024 +
                       (size_t)(i * 2 + (lq >> 1)) * 128 + (n & 15) * 8 + (lq & 1) * 4;
          *(short4v*)(&Kp[idx]) = pk;
        }
      }
    }
  } else {
#pragma unroll
    for (int i = 0; i < 4; i++) {
#pragma unroll
      for (int r = 0; r < 4; r++) {
        int o = o0 + wm * 64 + i * 16 + lq * 4 + r;
        int c = o - 128;
        float bias = bv[c];
#pragma unroll
        for (int j = 0; j < 4; j++) {
          int n = n0 + wn * 64 + j * 16 + lr;
          vbuf[((size_t)b * CC + c) * NN + n] = f2bf(acc[i][j][r] + bias);
        }
      }
    }
  }
}

// ---------------------------------------------------------------------------
// Kernel 3: flash (R11 body: V staged through LDS, counted vmcnt). THIS
//   ROUND: K-fragment loads read the Kp coalesced layout — one contiguous
//   2KB segment per wave per load (was 16 scattered 256B-strided lines).
//   Q fragments read Qb (loaded once; scatter negligible).
// ---------------------------------------------------------------------------
#define QT 64
#define MC 64
#define PSTR 72  // ushort units; 144B row stride (16B-aligned, 2-way banks = free)

__global__ __launch_bounds__(256, 2) void k_flash(
    const unsigned short* __restrict__ Qb, const unsigned short* __restrict__ Kp,
    const unsigned short* __restrict__ vbuf,
    const float* __restrict__ x, const float* __restrict__ gamma,
    float* __restrict__ out) {
  __shared__ __align__(16) unsigned short Vl[2][256 * 64];  // 65536 B
  __shared__ __align__(16) unsigned short P[QT * PSTR];     // 9216 B
  __shared__ float red[4 * QT];                             // 1024 B
  __shared__ float fin[QT];                                 // 256 B

  // XCD-aware swizzle: hw block h -> logical id (h%8)*64 + h/8 (512 = 8*64).
  int bid = blockIdx.x;
  int swz = (bid & 7) * 64 + (bid >> 3);
  int ntile = swz & 15;
  int chalf = (swz >> 4) & 1;
  int b = swz >> 5;
  int n0 = ntile * QT;
  int t = threadIdx.x;
  int w = t >> 6, l = t & 63;
  int lr = l & 15, lq = l >> 4;
  const unsigned short* Qbb = Qb + (size_t)b * NN * 64;
  const unsigned short* Kpb = Kp + (size_t)b * 65536;
  const unsigned short* Vg = vbuf + ((size_t)b * CC + chalf * 256) * NN;

  // --- V staging constants (R11) ---
  int chb = t >> 3;                              // 0..31
  int koff = ((t & 7) * 8) ^ ((chb & 7) << 3);   // pre-swizzled global src
  int sbase = w * 512;                           // wave-uniform LDS lane-0 offset

  // Q fragments (constant over all chunks)
  bf16x8 aq[4][2];
#pragma unroll
  for (int nj = 0; nj < 4; nj++)
#pragma unroll
    for (int ks = 0; ks < 2; ks++)
      aq[nj][ks] = *(const bf16x8*)(&Qbb[(size_t)(n0 + nj * 16 + lr) * 64 + ks * 32 + lq * 8]);

  f32x4 acc[4][4];  // [ci][nj]
#pragma unroll
  for (int ci = 0; ci < 4; ci++)
#pragma unroll
    for (int nj = 0; nj < 4; nj++) acc[ci][nj] = (f32x4){0.f, 0.f, 0.f, 0.f};
  float sreg[4][4];
#pragma unroll
  for (int nj = 0; nj < 4; nj++)
#pragma unroll
    for (int r = 0; r < 4; r++) sreg[nj][r] = 0.f;

  // Prologue: stage V(chunk 0) into buf 0.
#pragma unroll
  for (int g = 0; g < 8; g++)
    gll16(&Vg[(size_t)(g * 32 + chb) * NN + koff], &Vl[0][g * 2048 + sbase]);

  // Prologue: scores+exp for chunk 0 (Kp coalesced: group = w for m0=0).
  float ev[4][4];
  {
    const unsigned short* kb = &Kpb[(size_t)w * 1024 + lr * 8];
    bf16x8 kf0 = *(const bf16x8*)(&kb[lq * 128]);
    bf16x8 kf1 = *(const bf16x8*)(&kb[(lq + 4) * 128]);
#pragma unroll
    for (int nj = 0; nj < 4; nj++) {
      f32x4 s = (f32x4){0.f, 0.f, 0.f, 0.f};
      s = __builtin_amdgcn_mfma_f32_16x16x32_bf16(aq[nj][0], kf0, s, 0, 0, 0);
      s = __builtin_amdgcn_mfma_f32_16x16x32_bf16(aq[nj][1], kf1, s, 0, 0, 0);
#pragma unroll
      for (int r = 0; r < 4; r++) {
        float e = __expf(s[r]);
        ev[nj][r] = e;
        sreg[nj][r] += e;
      }
    }
  }

  int cur = 0;
  for (int m0 = 0; m0 < NN; m0 += MC, cur ^= 1) {
    bool hn = (m0 + MC < NN);
    // Next-chunk K fragments (coalesced 2KB/wave; ride across barrier1).
    bf16x8 kf0n, kf1n;
    if (hn) {
      const unsigned short* kb = &Kpb[(size_t)(((m0 + MC) >> 4) + w) * 1024 + lr * 8];
      kf0n = *(const bf16x8*)(&kb[lq * 128]);
      kf1n = *(const bf16x8*)(&kb[(lq + 4) * 128]);
    }

    // barrier1: prev chunk's PV reads (P and Vl[cur^1]) complete.
    asm volatile("s_waitcnt lgkmcnt(0)" ::: "memory");
    __builtin_amdgcn_sched_barrier(0);
    __builtin_amdgcn_s_barrier();

    // Stage V(next chunk) into Vl[cur^1].
    if (hn) {
#pragma unroll
      for (int g = 0; g < 8; g++)
        gll16(&Vg[(size_t)(g * 32 + chb) * NN + (m0 + MC) + koff],
              &Vl[cur ^ 1][g * 2048 + sbase]);
    }

    // P-write for this chunk.
#pragma unroll
    for (int nj = 0; nj < 4; nj++)
#pragma unroll
      for (int r = 0; r < 4; r++)
        P[(nj * 16 + lq * 4 + r) * PSTR + w * 16 + lr] = f2bf(ev[nj][r]);

    // Scores+exp for NEXT chunk while P settles.
    if (hn) {
#pragma unroll
      for (int nj = 0; nj < 4; nj++) {
        f32x4 s = (f32x4){0.f, 0.f, 0.f, 0.f};
        s = __builtin_amdgcn_mfma_f32_16x16x32_bf16(aq[nj][0], kf0n, s, 0, 0, 0);
        s = __builtin_amdgcn_mfma_f32_16x16x32_bf16(aq[nj][1], kf1n, s, 0, 0, 0);
#pragma unroll
        for (int r = 0; r < 4; r++) {
          float e = __expf(s[r]);
          ev[nj][r] = e;
          sreg[nj][r] += e;
        }
      }
    }

    // barrier2: P visible + Vl[cur] landed; next-chunk stage stays in flight.
    if (hn) {
      asm volatile("s_waitcnt vmcnt(8) lgkmcnt(0)" ::: "memory");
    } else {
      asm volatile("s_waitcnt vmcnt(0) lgkmcnt(0)" ::: "memory");
    }
    __builtin_amdgcn_sched_barrier(0);
    __builtin_amdgcn_s_barrier();

    // PV: V fragments from LDS (swizzled read), P fragments from LDS.
#pragma unroll
    for (int ks = 0; ks < 2; ks++) {
      bf16x8 vf[4];
#pragma unroll
      for (int ci = 0; ci < 4; ci++) {
        int row = w * 64 + ci * 16 + lr;
        int idx = row * 64 + (((ks * 32 + lq * 8)) ^ ((lr & 7) << 3));
        vf[ci] = *(const bf16x8*)(&Vl[cur][idx]);
      }
#pragma unroll
      for (int nj = 0; nj < 4; nj++) {
        bf16x8 pf = *(const bf16x8*)(&P[(nj * 16 + lr) * PSTR + ks * 32 + lq * 8]);
#pragma unroll
        for (int ci = 0; ci < 4; ci++)
          acc[ci][nj] = __builtin_amdgcn_mfma_f32_16x16x32_bf16(vf[ci], pf, acc[ci][nj], 0, 0, 0);
      }
    }
  }

  // ---- final row sums (across 16 lr lanes, then 4 waves) ----
#pragma unroll
  for (int nj = 0; nj < 4; nj++)
#pragma unroll
    for (int r = 0; r < 4; r++) {
#pragma unroll
      for (int d = 1; d < 16; d <<= 1) sreg[nj][r] += __shfl_xor(sreg[nj][r], d, 64);
    }
  __syncthreads();
  if (lr == 0) {
#pragma unroll
    for (int nj = 0; nj < 4; nj++)
#pragma unroll
      for (int r = 0; r < 4; r++) red[w * QT + nj * 16 + lq * 4 + r] = sreg[nj][r];
  }
  __syncthreads();
  if (t < QT) {
    float ssum = red[t] + red[QT + t] + red[2 * QT + t] + red[3 * QT + t];
    fin[t] = ssum;
  }
  __syncthreads();

  float invL[4];
#pragma unroll
  for (int nj = 0; nj < 4; nj++) invL[nj] = 1.0f / fin[nj * 16 + lr];
  float g = gamma[0];
#pragma unroll
  for (int ci = 0; ci < 4; ci++) {
#pragma unroll
    for (int r = 0; r < 4; r++) {
      int c = chalf * 256 + w * 64 + ci * 16 + lq * 4 + r;
#pragma unroll
      for (int nj = 0; nj < 4; nj++) {
        size_t idx = ((size_t)b * CC + c) * NN + n0 + nj * 16 + lr;
        out[idx] = g * acc[ci][nj][r] * invL[nj] + x[idx];
      }
    }
  }
}

// ---------------------------------------------------------------------------
extern "C" void kernel_launch(void* const* d_in, const int* in_sizes, int n_in,
                              void* d_out, int out_size, void* d_ws, size_t ws_size,
                              hipStream_t stream) {
  (void)in_sizes; (void)n_in; (void)out_size; (void)ws_size;
  const float* x     = (const float*)d_in[0];
  const float* Wq    = (const float*)d_in[1];
  const float* bq    = (const float*)d_in[2];
  const float* Wk    = (const float*)d_in[3];
  const float* bk    = (const float*)d_in[4];
  const float* Wv    = (const float*)d_in[5];
  const float* bv    = (const float*)d_in[6];
  const float* gamma = (const float*)d_in[7];
  float* out = (float*)d_out;

  char* ws = (char*)d_ws;
  unsigned short* Wall = (unsigned short*)(ws);                       // 655,360 B
  unsigned short* xT   = (unsigned short*)(ws + 655360);              // 16,777,216 B
  unsigned short* Qb   = (unsigned short*)(ws + 655360 + 16777216);   // 2,097,152 B
  unsigned short* Kp   = (unsigned short*)(ws + 655360 + 16777216 + 2097152);  // 2,097,152 B
  unsigned short* vbuf = (unsigned short*)(ws + 655360 + 16777216 + 2097152 + 2097152);  // 16,777,216 B
  // total ~38.4 MB

  k_prep<<<dim3(NN / 64, CC / 64, BB), dim3(256), 0, stream>>>(x, xT, Wq, Wk, Wv, Wall);
  k_gemm1<<<dim3(640), dim3(256), 0, stream>>>(Wall, xT, bq, bk, bv, Qb, Kp, vbuf);
  k_flash<<<dim3(512), dim3(256), 0, stream>>>(Qb, Kp, vbuf, x, gamma, out);
}